// Round 2
// baseline (575.989 us; speedup 1.0000x reference)
//
#include <hip/hip_runtime.h>

// ---------------- constants ----------------
__device__ __constant__ int GRADE_C[16] = {0,1,1,1,1,2,2,2,2,2,2,3,3,3,3,4};
__device__ __constant__ int INNER_C[8]  = {0,2,3,4,8,9,10,14};

// workspace layout (float indices)
#define OFF_QFT 0          // qfT[n][d(64)][h(8)] f32 : 1024*512
#define OFF_KF  524288     // kf[n][64] f32           : 1024*64
#define OFF_VC  589824     // Vc[n][96] (mv64+s32)    : 1024*96
#define OFF_GWB 688128     // gw[c(128)][h(8)] bf16 packed (512 floats of space)
#define OFF_GH  688640     // Gh[8] then Ch[8]
#define SB_BYTE 3145728    // bf16 s[q][k][h] : 1024*1024*8*2 = 16 MB

static __device__ __forceinline__ unsigned short f2bf(float f) {
    unsigned int u = __float_as_uint(f);
    u = u + 0x7fffu + ((u >> 16) & 1u);
    return (unsigned short)(u >> 16);
}
static __device__ __forceinline__ float bf2f(unsigned int b) {
    return __uint_as_float(b << 16);
}
static __device__ __forceinline__ float bflo(unsigned int u) {
    return __uint_as_float(u << 16);
}
static __device__ __forceinline__ float bfhi(unsigned int u) {
    return __uint_as_float(u & 0xffff0000u);
}

// ---------------- kernel P: projections ----------------
__global__ __launch_bounds__(256) void kproj(
    const float* __restrict__ mv, const float* __restrict__ s,
    const float* __restrict__ q_w_mv, const float* __restrict__ q_w_s,
    const float* __restrict__ k_w_mv, const float* __restrict__ k_w_s,
    const float* __restrict__ v_w_mv, const float* __restrict__ v_w_s,
    const float* __restrict__ ln_g, const float* __restrict__ ln_b,
    const float* __restrict__ bias_w, float* __restrict__ ws)
{
    __shared__ __align__(16) float mvn[256];    // [i][b] = i*16+b
    __shared__ __align__(16) float sn[128];
    __shared__ float qs_pre[256];
    __shared__ float ks_pre[32];
    __shared__ float vs_pre[32];
    const int n = blockIdx.x, t = threadIdx.x;

    mvn[t] = mv[n * 256 + t];
    if (t < 128) sn[t] = s[n * 128 + t];
    __syncthreads();

    // q_s pre-rope: 256 outputs, one per thread
    {
        const float4* w = (const float4*)(q_w_s + t * 128);
        const float4* sv = (const float4*)sn;
        float acc = 0.f;
        #pragma unroll
        for (int c4 = 0; c4 < 32; ++c4) {
            float4 wv = w[c4], x = sv[c4];
            acc += wv.x * x.x + wv.y * x.y + wv.z * x.z + wv.w * x.w;
        }
        qs_pre[t] = acc;
    }
    // k_s (t<32), v_s (32<=t<64)
    if (t < 64) {
        const float* wb = (t < 32) ? (k_w_s + t * 128) : (v_w_s + (t - 32) * 128);
        const float4* w = (const float4*)wb;
        const float4* sv = (const float4*)sn;
        float acc = 0.f;
        #pragma unroll
        for (int c4 = 0; c4 < 32; ++c4) {
            float4 wv = w[c4], x = sv[c4];
            acc += wv.x * x.x + wv.y * x.y + wv.z * x.z + wv.w * x.w;
        }
        if (t < 32) ks_pre[t] = acc; else vs_pre[t - 32] = acc;
    }
    // q_mv inner blades: o = t>>3 (0..31), j = t&7
    {
        int o = t >> 3, j = t & 7;
        int bx = INNER_C[j], g = GRADE_C[bx];
        float acc = 0.f;
        #pragma unroll
        for (int i = 0; i < 16; ++i)
            acc += mvn[i * 16 + bx] * q_w_mv[(o * 16 + i) * 5 + g];
        int h = o >> 2, c = o & 3, d = c * 8 + j;
        ws[OFF_QFT + n * 512 + d * 8 + h] = acc;
    }
    // k_mv inner: 32 outputs
    if (t < 32) {
        int c = t >> 3, j = t & 7, bx = INNER_C[j], g = GRADE_C[bx];
        float acc = 0.f;
        #pragma unroll
        for (int i = 0; i < 16; ++i)
            acc += mvn[i * 16 + bx] * k_w_mv[(c * 16 + i) * 5 + g];
        ws[OFF_KF + n * 64 + c * 8 + j] = acc;
    }
    // v_mv full 16 blades: 64 outputs (t in [64,128))
    if (t >= 64 && t < 128) {
        int idx = t - 64, c = idx >> 4, x = idx & 15, g = GRADE_C[x];
        float acc = 0.f;
        #pragma unroll
        for (int i = 0; i < 16; ++i)
            acc += mvn[i * 16 + x] * v_w_mv[(c * 16 + i) * 5 + g];
        ws[OFF_VC + n * 96 + c * 16 + x] = acc;
    }
    __syncthreads();

    // rope(q_s): h = t>>5, dd = t&31
    {
        int h = t >> 5, dd = t & 31, i = dd >> 1;
        float freq = exp2f(-0.75f * (float)i);
        float ang = (float)n * freq;
        float cv = cosf(ang), sv = sinf(ang);
        float x1 = qs_pre[h * 32 + 2 * i], x2 = qs_pre[h * 32 + 2 * i + 1];
        float val = ((dd & 1) == 0) ? (x1 * cv - x2 * sv) : (x1 * sv + x2 * cv);
        ws[OFF_QFT + n * 512 + (32 + dd) * 8 + h] = val;
    }
    // rope(k_s)
    if (t < 32) {
        int dd = t, i = dd >> 1;
        float freq = exp2f(-0.75f * (float)i);
        float ang = (float)n * freq;
        float cv = cosf(ang), sv = sinf(ang);
        float x1 = ks_pre[2 * i], x2 = ks_pre[2 * i + 1];
        float val = ((dd & 1) == 0) ? (x1 * cv - x2 * sv) : (x1 * sv + x2 * cv);
        ws[OFF_KF + n * 64 + 32 + dd] = val;
    }
    if (t >= 32 && t < 64) ws[OFF_VC + n * 96 + 64 + (t - 32)] = vs_pre[t - 32];

    // folded LN constants (block 0 only)
    if (n == 0) {
        if (t < 128) {
            float g = ln_g[t];
            unsigned short u[8];
            #pragma unroll
            for (int h = 0; h < 8; ++h)
                u[h] = f2bf(g * bias_w[t * 8 + h]);
            uint4 pk;
            pk.x = (unsigned)u[0] | ((unsigned)u[1] << 16);
            pk.y = (unsigned)u[2] | ((unsigned)u[3] << 16);
            pk.z = (unsigned)u[4] | ((unsigned)u[5] << 16);
            pk.w = (unsigned)u[6] | ((unsigned)u[7] << 16);
            *(uint4*)((unsigned int*)(ws + OFF_GWB) + t * 4) = pk;
        }
        if (t >= 128 && t < 136) {
            int h = t - 128;
            float gh = 0.f, ch = 0.f;
            for (int c = 0; c < 128; ++c) {
                gh += ln_g[c] * bias_w[c * 8 + h];
                ch += ln_b[c] * bias_w[c * 8 + h];
            }
            ws[OFF_GH + h] = gh;
            ws[OFF_GH + 8 + h] = ch;
        }
    }
}

// ---------------- kernel A: fused LN-bias + logits -> s (bf16) ----------------
// 2 rows per thread, bf16 gw in LDS: 4x less LDS traffic per z element.
__global__ __launch_bounds__(256, 4) void kbias(
    const float* __restrict__ z, float* __restrict__ ws)
{
    __shared__ __align__(16) float qft[512];           // [d(64)][h(8)] f32
    __shared__ __align__(16) unsigned int gwb[512];    // [c(128)][h(8)] bf16 packed
    __shared__ float GhCh[16];
    const int blk = blockIdx.x;
    const int q = blk >> 2, kt = blk & 3;
    const int t = threadIdx.x;

    if (t < 128) {
        ((float4*)qft)[t] = ((const float4*)(ws + OFF_QFT + q * 512))[t];
        if (t < 16) GhCh[t] = ws[OFF_GH + t];
    } else {
        int i = t - 128;
        ((uint4*)gwb)[i] = ((const uint4*)((const unsigned int*)(ws + OFF_GWB)))[i];
    }
    __syncthreads();

    const int pair = t >> 1, half = t & 1;
    const int k = kt * 256 + pair * 2;        // this thread: rows k, k+1 (channel half)

    const float* zr0 = z + ((size_t)q * 1024 + k) * 128 + half * 64;
    const float* zr1 = zr0 + 128;

    float sum0 = 0.f, sumsq0 = 0.f, sum1 = 0.f, sumsq1 = 0.f;
    float dg0[8] = {0,0,0,0,0,0,0,0}, dg1[8] = {0,0,0,0,0,0,0,0};
    float dq0[8] = {0,0,0,0,0,0,0,0}, dq1[8] = {0,0,0,0,0,0,0,0};

    const uint4* gwv = (const uint4*)gwb;

    // ---- dg / sum / sumsq over this thread's 64 channels x 2 rows ----
    #pragma unroll
    for (int ch = 0; ch < 8; ++ch) {
        float4 a0 = ((const float4*)zr0)[ch * 2];
        float4 a1 = ((const float4*)zr0)[ch * 2 + 1];
        float4 b0 = ((const float4*)zr1)[ch * 2];
        float4 b1 = ((const float4*)zr1)[ch * 2 + 1];
        float za[8] = {a0.x, a0.y, a0.z, a0.w, a1.x, a1.y, a1.z, a1.w};
        float zb[8] = {b0.x, b0.y, b0.z, b0.w, b1.x, b1.y, b1.z, b1.w};
        #pragma unroll
        for (int j = 0; j < 8; ++j) {
            int c = half * 64 + ch * 8 + j;
            uint4 gv = gwv[c];
            float g0 = bflo(gv.x), g1 = bfhi(gv.x);
            float g2 = bflo(gv.y), g3 = bfhi(gv.y);
            float g4 = bflo(gv.z), g5 = bfhi(gv.z);
            float g6 = bflo(gv.w), g7 = bfhi(gv.w);
            float x = za[j], y = zb[j];
            sum0 += x; sumsq0 = __builtin_fmaf(x, x, sumsq0);
            sum1 += y; sumsq1 = __builtin_fmaf(y, y, sumsq1);
            dg0[0] = __builtin_fmaf(x, g0, dg0[0]); dg1[0] = __builtin_fmaf(y, g0, dg1[0]);
            dg0[1] = __builtin_fmaf(x, g1, dg0[1]); dg1[1] = __builtin_fmaf(y, g1, dg1[1]);
            dg0[2] = __builtin_fmaf(x, g2, dg0[2]); dg1[2] = __builtin_fmaf(y, g2, dg1[2]);
            dg0[3] = __builtin_fmaf(x, g3, dg0[3]); dg1[3] = __builtin_fmaf(y, g3, dg1[3]);
            dg0[4] = __builtin_fmaf(x, g4, dg0[4]); dg1[4] = __builtin_fmaf(y, g4, dg1[4]);
            dg0[5] = __builtin_fmaf(x, g5, dg0[5]); dg1[5] = __builtin_fmaf(y, g5, dg1[5]);
            dg0[6] = __builtin_fmaf(x, g6, dg0[6]); dg1[6] = __builtin_fmaf(y, g6, dg1[6]);
            dg0[7] = __builtin_fmaf(x, g7, dg0[7]); dg1[7] = __builtin_fmaf(y, g7, dg1[7]);
        }
    }

    // ---- dq (logits) over this thread's 32 d x 2 rows ----
    const float* kf0 = ws + OFF_KF + (size_t)k * 64 + half * 32;
    const float* kf1 = kf0 + 64;
    const float4* qfv = (const float4*)qft;
    #pragma unroll
    for (int dc = 0; dc < 8; ++dc) {
        float4 kA = ((const float4*)kf0)[dc];
        float4 kB = ((const float4*)kf1)[dc];
        float ka[4] = {kA.x, kA.y, kA.z, kA.w};
        float kb[4] = {kB.x, kB.y, kB.z, kB.w};
        #pragma unroll
        for (int j = 0; j < 4; ++j) {
            int d = half * 32 + dc * 4 + j;
            float4 q0 = qfv[d * 2], q1 = qfv[d * 2 + 1];
            float x = ka[j], y = kb[j];
            dq0[0] = __builtin_fmaf(x, q0.x, dq0[0]); dq1[0] = __builtin_fmaf(y, q0.x, dq1[0]);
            dq0[1] = __builtin_fmaf(x, q0.y, dq0[1]); dq1[1] = __builtin_fmaf(y, q0.y, dq1[1]);
            dq0[2] = __builtin_fmaf(x, q0.z, dq0[2]); dq1[2] = __builtin_fmaf(y, q0.z, dq1[2]);
            dq0[3] = __builtin_fmaf(x, q0.w, dq0[3]); dq1[3] = __builtin_fmaf(y, q0.w, dq1[3]);
            dq0[4] = __builtin_fmaf(x, q1.x, dq0[4]); dq1[4] = __builtin_fmaf(y, q1.x, dq1[4]);
            dq0[5] = __builtin_fmaf(x, q1.y, dq0[5]); dq1[5] = __builtin_fmaf(y, q1.y, dq1[5]);
            dq0[6] = __builtin_fmaf(x, q1.z, dq0[6]); dq1[6] = __builtin_fmaf(y, q1.z, dq1[6]);
            dq0[7] = __builtin_fmaf(x, q1.w, dq0[7]); dq1[7] = __builtin_fmaf(y, q1.w, dq1[7]);
        }
    }

    // ---- combine channel halves (lane pair) ----
    sum0 += __shfl_xor(sum0, 1);  sumsq0 += __shfl_xor(sumsq0, 1);
    sum1 += __shfl_xor(sum1, 1);  sumsq1 += __shfl_xor(sumsq1, 1);
    #pragma unroll
    for (int h = 0; h < 8; ++h) {
        dg0[h] += __shfl_xor(dg0[h], 1);
        dg1[h] += __shfl_xor(dg1[h], 1);
        dq0[h] += __shfl_xor(dq0[h], 1);
        dq1[h] += __shfl_xor(dq1[h], 1);
    }

    // ---- each lane finalizes + writes its own row (k + half): coalesced ----
    float S   = half ? sum1   : sum0;
    float SS  = half ? sumsq1 : sumsq0;
    float mean = S * (1.f / 128.f);
    float var  = SS * (1.f / 128.f) - mean * mean;
    float rs   = rsqrtf(var + 1e-5f);
    unsigned short u[8];
    #pragma unroll
    for (int h = 0; h < 8; ++h) {
        float dgS = half ? dg1[h] : dg0[h];
        float dqS = half ? dq1[h] : dq0[h];
        float bias = rs * (dgS - mean * GhCh[h]) + GhCh[8 + h];
        u[h] = f2bf(dqS * 0.125f + bias);
    }
    uint4 pk;
    pk.x = (unsigned)u[0] | ((unsigned)u[1] << 16);
    pk.y = (unsigned)u[2] | ((unsigned)u[3] << 16);
    pk.z = (unsigned)u[4] | ((unsigned)u[5] << 16);
    pk.w = (unsigned)u[6] | ((unsigned)u[7] << 16);
    unsigned short* sb = (unsigned short*)((char*)ws + SB_BYTE);
    *(uint4*)(sb + ((size_t)q * 1024 + (k + half)) * 8) = pk;
}

// ---------------- kernel B: softmax + PV + output projections ----------------
__global__ __launch_bounds__(256) void kattn(
    const float* __restrict__ ws,
    const float* __restrict__ out_w_mv, const float* __restrict__ out_w_s,
    float* __restrict__ d_out)
{
    __shared__ __align__(16) float Sl[8 * 1024];  // [h][k]
    __shared__ float inv_l[8];
    __shared__ float o_sh[8 * 96];
    const int q = blockIdx.x, t = threadIdx.x;

    const unsigned short* sb =
        (const unsigned short*)((const char*)ws + SB_BYTE) + (size_t)q * 8192;
    #pragma unroll
    for (int it = 0; it < 4; ++it) {
        int k = t + it * 256;
        uint4 rv = *(const uint4*)(sb + (size_t)k * 8);
        Sl[0 * 1024 + k] = bf2f(rv.x & 0xffffu);
        Sl[1 * 1024 + k] = bf2f(rv.x >> 16);
        Sl[2 * 1024 + k] = bf2f(rv.y & 0xffffu);
        Sl[3 * 1024 + k] = bf2f(rv.y >> 16);
        Sl[4 * 1024 + k] = bf2f(rv.z & 0xffffu);
        Sl[5 * 1024 + k] = bf2f(rv.z >> 16);
        Sl[6 * 1024 + k] = bf2f(rv.w & 0xffffu);
        Sl[7 * 1024 + k] = bf2f(rv.w >> 16);
    }
    __syncthreads();

    const int h = t >> 5, e = t & 31;
    // per-head max (32 lanes per head)
    float m = -1e30f;
    #pragma unroll 8
    for (int j = 0; j < 32; ++j) m = fmaxf(m, Sl[h * 1024 + e + j * 32]);
    #pragma unroll
    for (int d = 16; d >= 1; d >>= 1) m = fmaxf(m, __shfl_xor(m, d));
    // exp + sum (write p back unnormalized)
    float lsum = 0.f;
    #pragma unroll 8
    for (int j = 0; j < 32; ++j) {
        int kk = e + j * 32;
        float p = __expf(Sl[h * 1024 + kk] - m);
        Sl[h * 1024 + kk] = p;
        lsum += p;
    }
    #pragma unroll
    for (int d = 16; d >= 1; d >>= 1) lsum += __shfl_xor(lsum, d);
    if (e == 0) inv_l[h] = 1.f / lsum;
    __syncthreads();

    // PV: thread (h,e) accumulates elems e, e+32, e+64 over all k
    const float* Vc = ws + OFF_VC;
    const float* Ph = &Sl[h * 1024];
    float a0 = 0.f, a1 = 0.f, a2 = 0.f;
    for (int k0 = 0; k0 < 1024; k0 += 4) {
        float4 p4 = *(const float4*)(Ph + k0);
        float pv[4] = {p4.x, p4.y, p4.z, p4.w};
        #pragma unroll
        for (int j = 0; j < 4; ++j) {
            const float* vr = Vc + (size_t)(k0 + j) * 96 + e;
            a0 += pv[j] * vr[0];
            a1 += pv[j] * vr[32];
            a2 += pv[j] * vr[64];
        }
    }
    float il = inv_l[h];
    o_sh[h * 96 + e]      = a0 * il;
    o_sh[h * 96 + e + 32] = a1 * il;
    o_sh[h * 96 + e + 64] = a2 * il;
    __syncthreads();

    // out_mv: 256 outputs: o2 = t>>4, b = t&15
    {
        int o2 = t >> 4, b = t & 15, g = GRADE_C[b];
        float acc = 0.f;
        #pragma unroll
        for (int i = 0; i < 32; ++i)
            acc += o_sh[(i >> 2) * 96 + (i & 3) * 16 + b] *
                   out_w_mv[(o2 * 32 + i) * 5 + g];
        d_out[(q * 16 + o2) * 16 + b] = acc;
    }
    // out_s: 128 outputs
    if (t < 128) {
        const float* w = out_w_s + t * 256;
        float acc = 0.f;
        #pragma unroll 4
        for (int c = 0; c < 256; ++c)
            acc += o_sh[(c >> 5) * 96 + 64 + (c & 31)] * w[c];
        d_out[262144 + q * 128 + t] = acc;
    }
}

// ---------------- launch ----------------
extern "C" void kernel_launch(void* const* d_in, const int* in_sizes, int n_in,
                              void* d_out, int out_size, void* d_ws, size_t ws_size,
                              hipStream_t stream) {
    (void)in_sizes; (void)n_in; (void)out_size; (void)ws_size;
    const float* mv       = (const float*)d_in[0];
    const float* s        = (const float*)d_in[1];
    const float* z        = (const float*)d_in[2];
    const float* q_w_mv   = (const float*)d_in[3];
    const float* q_w_s    = (const float*)d_in[4];
    const float* k_w_mv   = (const float*)d_in[5];
    const float* k_w_s    = (const float*)d_in[6];
    const float* v_w_mv   = (const float*)d_in[7];
    const float* v_w_s    = (const float*)d_in[8];
    const float* out_w_mv = (const float*)d_in[9];
    const float* out_w_s  = (const float*)d_in[10];
    const float* ln_g     = (const float*)d_in[11];
    const float* ln_b     = (const float*)d_in[12];
    const float* bias_w   = (const float*)d_in[13];
    float* ws  = (float*)d_ws;
    float* out = (float*)d_out;

    kproj<<<1024, 256, 0, stream>>>(mv, s, q_w_mv, q_w_s, k_w_mv, k_w_s,
                                    v_w_mv, v_w_s, ln_g, ln_b, bias_w, ws);
    kbias<<<4096, 256, 0, stream>>>(z, ws);
    kattn<<<1024, 256, 0, stream>>>(ws, out_w_mv, out_w_s, out);
}

// Round 3
// 285.467 us; speedup vs baseline: 2.0177x; 2.0177x over previous
//
#include <hip/hip_runtime.h>

// ---------------- constants ----------------
__device__ __constant__ int GRADE_C[16] = {0,1,1,1,1,2,2,2,2,2,2,3,3,3,3,4};
__device__ __constant__ int INNER_C[8]  = {0,2,3,4,8,9,10,14};

// workspace layout
#define OFF_VC   0          // Vc[n][96] f32 (mv64 + s32)     : 98304 floats
#define OFF_GH   98304      // Gh[8] then Ch[8] f32
#define KFB_BYTE 393280     // kf[n][64] bf16                  : 128 KB
#define QFB_BYTE 524352     // qfb[q][j(16)][d(64)] bf16       : 2 MB
#define GWBT_BYTE 2621504   // gwBT[j(16)][c(128)] bf16        : 4 KB
#define SB_BYTE  3145728    // s[q][k][h(8)] bf16              : 16 MB

typedef __attribute__((ext_vector_type(8))) short bf16x8;
typedef __attribute__((ext_vector_type(4))) float f32x4;
typedef __attribute__((ext_vector_type(4))) unsigned int u32x4;

static __device__ __forceinline__ unsigned short f2bf(float f) {
    unsigned int u = __float_as_uint(f);
    u = u + 0x7fffu + ((u >> 16) & 1u);
    return (unsigned short)(u >> 16);
}
static __device__ __forceinline__ unsigned pk2(float lo, float hi) {
    return (unsigned)f2bf(lo) | ((unsigned)f2bf(hi) << 16);
}
static __device__ __forceinline__ float bf2f(unsigned int b) {
    return __uint_as_float(b << 16);
}

// ---------------- kernel P: projections ----------------
__global__ __launch_bounds__(256) void kproj(
    const float* __restrict__ mv, const float* __restrict__ s,
    const float* __restrict__ q_w_mv, const float* __restrict__ q_w_s,
    const float* __restrict__ k_w_mv, const float* __restrict__ k_w_s,
    const float* __restrict__ v_w_mv, const float* __restrict__ v_w_s,
    const float* __restrict__ ln_g, const float* __restrict__ ln_b,
    const float* __restrict__ bias_w, float* __restrict__ ws)
{
    __shared__ __align__(16) float mvn[256];
    __shared__ __align__(16) float sn[128];
    __shared__ float qs_pre[256];
    __shared__ float ks_pre[32];
    __shared__ float vs_pre[32];
    const int n = blockIdx.x, t = threadIdx.x;

    unsigned short* kfb = (unsigned short*)((char*)ws + KFB_BYTE);
    unsigned short* qfb = (unsigned short*)((char*)ws + QFB_BYTE);
    unsigned short* gwp = (unsigned short*)((char*)ws + GWBT_BYTE);

    mvn[t] = mv[n * 256 + t];
    if (t < 128) sn[t] = s[n * 128 + t];
    __syncthreads();

    // q_s pre-rope: 256 outputs
    {
        const float4* w = (const float4*)(q_w_s + t * 128);
        const float4* sv = (const float4*)sn;
        float acc = 0.f;
        #pragma unroll
        for (int c4 = 0; c4 < 32; ++c4) {
            float4 wv = w[c4], x = sv[c4];
            acc += wv.x * x.x + wv.y * x.y + wv.z * x.z + wv.w * x.w;
        }
        qs_pre[t] = acc;
    }
    if (t < 64) {
        const float* wb = (t < 32) ? (k_w_s + t * 128) : (v_w_s + (t - 32) * 128);
        const float4* w = (const float4*)wb;
        const float4* sv = (const float4*)sn;
        float acc = 0.f;
        #pragma unroll
        for (int c4 = 0; c4 < 32; ++c4) {
            float4 wv = w[c4], x = sv[c4];
            acc += wv.x * x.x + wv.y * x.y + wv.z * x.z + wv.w * x.w;
        }
        if (t < 32) ks_pre[t] = acc; else vs_pre[t - 32] = acc;
    }
    // q_mv inner blades -> qfb[q][h][d], d = c*8+j in [0,32)
    {
        int o = t >> 3, j = t & 7;
        int bx = INNER_C[j], g = GRADE_C[bx];
        float acc = 0.f;
        #pragma unroll
        for (int i = 0; i < 16; ++i)
            acc += mvn[i * 16 + bx] * q_w_mv[(o * 16 + i) * 5 + g];
        int h = o >> 2, c = o & 3, d = c * 8 + j;
        qfb[n * 1024 + h * 64 + d] = f2bf(acc);
    }
    // zero-fill qfb cols j=8..15
    {
        int hp = 8 + (t >> 5), d = t & 31;
        qfb[n * 1024 + hp * 64 + d] = 0;
        qfb[n * 1024 + hp * 64 + 32 + d] = 0;
    }
    // k_mv inner -> kfb[n][d], d = t in [0,32)
    if (t < 32) {
        int bx = INNER_C[t & 7], g = GRADE_C[bx];
        float acc = 0.f;
        #pragma unroll
        for (int i = 0; i < 16; ++i)
            acc += mvn[i * 16 + bx] * k_w_mv[((t >> 3) * 16 + i) * 5 + g];
        kfb[n * 64 + t] = f2bf(acc);
    }
    // v_mv full 16 blades -> Vc
    if (t >= 64 && t < 128) {
        int idx = t - 64, c = idx >> 4, x = idx & 15, g = GRADE_C[x];
        float acc = 0.f;
        #pragma unroll
        for (int i = 0; i < 16; ++i)
            acc += mvn[i * 16 + x] * v_w_mv[(c * 16 + i) * 5 + g];
        ws[OFF_VC + n * 96 + c * 16 + x] = acc;
    }
    __syncthreads();

    // rope(q_s) -> qfb[q][h][32+dd]
    {
        int h = t >> 5, dd = t & 31, i = dd >> 1;
        float freq = exp2f(-0.75f * (float)i);
        float ang = (float)n * freq;
        float cv = cosf(ang), sv = sinf(ang);
        float x1 = qs_pre[h * 32 + 2 * i], x2 = qs_pre[h * 32 + 2 * i + 1];
        float val = ((dd & 1) == 0) ? (x1 * cv - x2 * sv) : (x1 * sv + x2 * cv);
        qfb[n * 1024 + h * 64 + 32 + dd] = f2bf(val);
    }
    // rope(k_s) -> kfb[n][32+dd]
    if (t < 32) {
        int i = t >> 1;
        float freq = exp2f(-0.75f * (float)i);
        float ang = (float)n * freq;
        float cv = cosf(ang), sv = sinf(ang);
        float x1 = ks_pre[2 * i], x2 = ks_pre[2 * i + 1];
        float val = ((t & 1) == 0) ? (x1 * cv - x2 * sv) : (x1 * sv + x2 * cv);
        kfb[n * 64 + 32 + t] = f2bf(val);
    }
    if (t >= 32 && t < 64) ws[OFF_VC + n * 96 + 64 + (t - 32)] = vs_pre[t - 32];

    // folded LN constants + gwBT (block 0 only)
    if (n == 0) {
        if (t < 128) {
            float g = ln_g[t];
            #pragma unroll
            for (int j = 0; j < 8; ++j)
                gwp[j * 128 + t] = f2bf(g * bias_w[t * 8 + j]);
            gwp[8 * 128 + t] = 0x3F80;  // ones column -> row sum
            #pragma unroll
            for (int j = 9; j < 16; ++j) gwp[j * 128 + t] = 0;
        }
        if (t >= 128 && t < 136) {
            int h = t - 128;
            float gh = 0.f, ch = 0.f;
            for (int c = 0; c < 128; ++c) {
                gh += ln_g[c] * bias_w[c * 8 + h];
                ch += ln_b[c] * bias_w[c * 8 + h];
            }
            ws[OFF_GH + h] = gh;
            ws[OFF_GH + 8 + h] = ch;
        }
    }
}

// ---------------- kernel A: MFMA fused LN-bias + logits -> s (bf16) ----------------
// block: one q x 128 k-rows. dg & dq on matrix cores; z fragments straight from global.
__global__ __launch_bounds__(256, 4) void kbias(
    const float* __restrict__ z, float* __restrict__ ws)
{
    __shared__ float d1[128][17];   // dg cols 0-7, sum col 8
    __shared__ float d2[128][17];   // dq cols 0-7
    __shared__ float ssq[128];
    const int blk = blockIdx.x;
    const int q = blk >> 3, kblk = blk & 7;
    const int t = threadIdx.x, w = t >> 6, l = t & 63;
    const int lm = l & 15, lg = l >> 4;

    // B fragments (per-lane 16B contiguous, L2-resident)
    bf16x8 B1[4], B2[2];
    #pragma unroll
    for (int ks = 0; ks < 4; ++ks)
        B1[ks] = *(const bf16x8*)((const char*)ws + GWBT_BYTE + (lm * 128 + ks * 32 + lg * 8) * 2);
    #pragma unroll
    for (int ds = 0; ds < 2; ++ds)
        B2[ds] = *(const bf16x8*)((const char*)ws + QFB_BYTE + ((size_t)q * 1024 + lm * 64 + ds * 32 + lg * 8) * 2);

    #pragma unroll
    for (int mi = 0; mi < 2; ++mi) {
        const int mt = w * 2 + mi;
        const int krow = kblk * 128 + mt * 16 + lm;
        const float* zr = z + ((size_t)q * 1024 + krow) * 128 + lg * 8;
        float4 za[4], zb[4];
        #pragma unroll
        for (int ks = 0; ks < 4; ++ks) {
            za[ks] = *(const float4*)(zr + ks * 32);
            zb[ks] = *(const float4*)(zr + ks * 32 + 4);
        }
        bf16x8 A2[2];
        #pragma unroll
        for (int ds = 0; ds < 2; ++ds)
            A2[ds] = *(const bf16x8*)((const char*)ws + KFB_BYTE + ((size_t)krow * 64 + ds * 32 + lg * 8) * 2);

        f32x4 acc1 = {0.f, 0.f, 0.f, 0.f};
        f32x4 acc2 = {0.f, 0.f, 0.f, 0.f};
        float sq = 0.f;
        #pragma unroll
        for (int ks = 0; ks < 4; ++ks) {
            float xs[8] = {za[ks].x, za[ks].y, za[ks].z, za[ks].w,
                           zb[ks].x, zb[ks].y, zb[ks].z, zb[ks].w};
            #pragma unroll
            for (int e = 0; e < 8; ++e) sq = __builtin_fmaf(xs[e], xs[e], sq);
            u32x4 au;
            au[0] = pk2(xs[0], xs[1]); au[1] = pk2(xs[2], xs[3]);
            au[2] = pk2(xs[4], xs[5]); au[3] = pk2(xs[6], xs[7]);
            bf16x8 af = __builtin_bit_cast(bf16x8, au);
            acc1 = __builtin_amdgcn_mfma_f32_16x16x32_bf16(af, B1[ks], acc1, 0, 0, 0);
        }
        acc2 = __builtin_amdgcn_mfma_f32_16x16x32_bf16(A2[0], B2[0], acc2, 0, 0, 0);
        acc2 = __builtin_amdgcn_mfma_f32_16x16x32_bf16(A2[1], B2[1], acc2, 0, 0, 0);

        // sumsq: combine the 4 lane groups (each holds 32 of 128 channels of row lm)
        sq += __shfl_xor(sq, 16);
        sq += __shfl_xor(sq, 32);
        if (lg == 0) ssq[mt * 16 + lm] = sq;

        #pragma unroll
        for (int r = 0; r < 4; ++r) {
            int row = mt * 16 + lg * 4 + r;
            d1[row][lm] = acc1[r];
            d2[row][lm] = acc2[r];
        }
    }
    __syncthreads();

    // finalize: thread -> (row r = t>>1, h-block hb = t&1)
    {
        const int r = t >> 1, hb = t & 1;
        float sum = d1[r][8];
        float sq = ssq[r];
        float mean = sum * (1.f / 128.f);
        float var = sq * (1.f / 128.f) - mean * mean;
        float rs = rsqrtf(var + 1e-5f);
        unsigned short u[4];
        #pragma unroll
        for (int j = 0; j < 4; ++j) {
            int h = hb * 4 + j;
            float bias = rs * (d1[r][h] - mean * ws[OFF_GH + h]) + ws[OFF_GH + 8 + h];
            u[j] = f2bf(d2[r][h] * 0.125f + bias);
        }
        uint2 pk;
        pk.x = (unsigned)u[0] | ((unsigned)u[1] << 16);
        pk.y = (unsigned)u[2] | ((unsigned)u[3] << 16);
        unsigned short* sb = (unsigned short*)((char*)ws + SB_BYTE);
        *(uint2*)(sb + ((size_t)q * 1024 + kblk * 128 + r) * 8 + hb * 4) = pk;
    }
}

// ---------------- kernel B: softmax + PV + output projections ----------------
__global__ __launch_bounds__(256) void kattn(
    const float* __restrict__ ws,
    const float* __restrict__ out_w_mv, const float* __restrict__ out_w_s,
    float* __restrict__ d_out)
{
    __shared__ __align__(16) float Sl[8 * 1024];  // [h][k]
    __shared__ float inv_l[8];
    __shared__ float o_sh[8 * 96];
    const int q = blockIdx.x, t = threadIdx.x;

    const unsigned short* sb =
        (const unsigned short*)((const char*)ws + SB_BYTE) + (size_t)q * 8192;
    #pragma unroll
    for (int it = 0; it < 4; ++it) {
        int k = t + it * 256;
        uint4 rv = *(const uint4*)(sb + (size_t)k * 8);
        Sl[0 * 1024 + k] = bf2f(rv.x & 0xffffu);
        Sl[1 * 1024 + k] = bf2f(rv.x >> 16);
        Sl[2 * 1024 + k] = bf2f(rv.y & 0xffffu);
        Sl[3 * 1024 + k] = bf2f(rv.y >> 16);
        Sl[4 * 1024 + k] = bf2f(rv.z & 0xffffu);
        Sl[5 * 1024 + k] = bf2f(rv.z >> 16);
        Sl[6 * 1024 + k] = bf2f(rv.w & 0xffffu);
        Sl[7 * 1024 + k] = bf2f(rv.w >> 16);
    }
    __syncthreads();

    const int h = t >> 5, e = t & 31;
    float m = -1e30f;
    #pragma unroll 8
    for (int j = 0; j < 32; ++j) m = fmaxf(m, Sl[h * 1024 + e + j * 32]);
    #pragma unroll
    for (int d = 16; d >= 1; d >>= 1) m = fmaxf(m, __shfl_xor(m, d));
    float lsum = 0.f;
    #pragma unroll 8
    for (int j = 0; j < 32; ++j) {
        int kk = e + j * 32;
        float p = __expf(Sl[h * 1024 + kk] - m);
        Sl[h * 1024 + kk] = p;
        lsum += p;
    }
    #pragma unroll
    for (int d = 16; d >= 1; d >>= 1) lsum += __shfl_xor(lsum, d);
    if (e == 0) inv_l[h] = 1.f / lsum;
    __syncthreads();

    // PV: 24 active lanes per head, each owns 4 consecutive V-columns (float4 loads)
    const float* Vc = ws + OFF_VC;
    const float* Ph = &Sl[h * 1024];
    if (e < 24) {
        float a0 = 0.f, a1 = 0.f, a2 = 0.f, a3 = 0.f;
        const float* vb = Vc + e * 4;
        for (int k0 = 0; k0 < 1024; k0 += 4) {
            float4 p4 = *(const float4*)(Ph + k0);
            float pj[4] = {p4.x, p4.y, p4.z, p4.w};
            #pragma unroll
            for (int j = 0; j < 4; ++j) {
                float4 v = *(const float4*)(vb + (size_t)(k0 + j) * 96);
                a0 = __builtin_fmaf(pj[j], v.x, a0);
                a1 = __builtin_fmaf(pj[j], v.y, a1);
                a2 = __builtin_fmaf(pj[j], v.z, a2);
                a3 = __builtin_fmaf(pj[j], v.w, a3);
            }
        }
        float il = inv_l[h];
        o_sh[h * 96 + e * 4 + 0] = a0 * il;
        o_sh[h * 96 + e * 4 + 1] = a1 * il;
        o_sh[h * 96 + e * 4 + 2] = a2 * il;
        o_sh[h * 96 + e * 4 + 3] = a3 * il;
    }
    __syncthreads();

    // out_mv: 256 outputs
    {
        int o2 = t >> 4, b = t & 15, g = GRADE_C[b];
        float acc = 0.f;
        #pragma unroll
        for (int i = 0; i < 32; ++i)
            acc += o_sh[(i >> 2) * 96 + (i & 3) * 16 + b] *
                   out_w_mv[(o2 * 32 + i) * 5 + g];
        d_out[(q * 16 + o2) * 16 + b] = acc;
    }
    // out_s: 128 outputs
    if (t < 128) {
        const float* wv = out_w_s + t * 256;
        float acc = 0.f;
        #pragma unroll 4
        for (int c = 0; c < 256; ++c)
            acc += o_sh[(c >> 5) * 96 + 64 + (c & 31)] * wv[c];
        d_out[262144 + q * 128 + t] = acc;
    }
}

// ---------------- launch ----------------
extern "C" void kernel_launch(void* const* d_in, const int* in_sizes, int n_in,
                              void* d_out, int out_size, void* d_ws, size_t ws_size,
                              hipStream_t stream) {
    (void)in_sizes; (void)n_in; (void)out_size; (void)ws_size;
    const float* mv       = (const float*)d_in[0];
    const float* s        = (const float*)d_in[1];
    const float* z        = (const float*)d_in[2];
    const float* q_w_mv   = (const float*)d_in[3];
    const float* q_w_s    = (const float*)d_in[4];
    const float* k_w_mv   = (const float*)d_in[5];
    const float* k_w_s    = (const float*)d_in[6];
    const float* v_w_mv   = (const float*)d_in[7];
    const float* v_w_s    = (const float*)d_in[8];
    const float* out_w_mv = (const float*)d_in[9];
    const float* out_w_s  = (const float*)d_in[10];
    const float* ln_g     = (const float*)d_in[11];
    const float* ln_b     = (const float*)d_in[12];
    const float* bias_w   = (const float*)d_in[13];
    float* ws  = (float*)d_ws;
    float* out = (float*)d_out;

    kproj<<<1024, 256, 0, stream>>>(mv, s, q_w_mv, q_w_s, k_w_mv, k_w_s,
                                    v_w_mv, v_w_s, ln_g, ln_b, bias_w, ws);
    kbias<<<8192, 256, 0, stream>>>(z, ws);
    kattn<<<1024, 256, 0, stream>>>(ws, out_w_mv, out_w_s, out);
}

// Round 4
// 194.165 us; speedup vs baseline: 2.9665x; 1.4702x over previous
//
#include <hip/hip_runtime.h>

// ---------------- constants ----------------
__device__ __constant__ int GRADE_C[16] = {0,1,1,1,1,2,2,2,2,2,2,3,3,3,3,4};
__device__ __constant__ int INNER_C[8]  = {0,2,3,4,8,9,10,14};

// workspace layout (bytes unless noted)
#define OFF_GH    0         // float idx 0..15: Gh[8], Ch[8]
#define GWBT_BYTE 4096      // gwBT[j(16)][c(128)] bf16, k-slot PERMUTED : 4 KB
#define KFB_BYTE  16384     // kf[n][64] bf16                            : 128 KB
#define VTB_BYTE  262144    // Vt[comp(96)][n(1024)] bf16                : 192 KB
#define QFB_BYTE  524288    // qfb[q][j(16)][d(64)] bf16                 : 2 MB
#define SB_BYTE   3145728   // s[q][k][h(8)] bf16                        : 16 MB

typedef __attribute__((ext_vector_type(8))) short bf16x8;
typedef __attribute__((ext_vector_type(4))) float f32x4;
typedef __attribute__((ext_vector_type(4))) unsigned int u32x4;

static __device__ __forceinline__ unsigned short f2bf(float f) {
    unsigned int u = __float_as_uint(f);
    u = u + 0x7fffu + ((u >> 16) & 1u);
    return (unsigned short)(u >> 16);
}
static __device__ __forceinline__ unsigned pk2(float lo, float hi) {
    return (unsigned)f2bf(lo) | ((unsigned)f2bf(hi) << 16);
}
static __device__ __forceinline__ float bflo(unsigned int u) {
    return __uint_as_float(u << 16);
}
static __device__ __forceinline__ float bfhi(unsigned int u) {
    return __uint_as_float(u & 0xffff0000u);
}

// ---------------- kernel P: projections ----------------
__global__ __launch_bounds__(256) void kproj(
    const float* __restrict__ mv, const float* __restrict__ s,
    const float* __restrict__ q_w_mv, const float* __restrict__ q_w_s,
    const float* __restrict__ k_w_mv, const float* __restrict__ k_w_s,
    const float* __restrict__ v_w_mv, const float* __restrict__ v_w_s,
    const float* __restrict__ ln_g, const float* __restrict__ ln_b,
    const float* __restrict__ bias_w, float* __restrict__ ws)
{
    __shared__ __align__(16) float mvn[256];
    __shared__ __align__(16) float sn[128];
    __shared__ float qs_pre[256];
    __shared__ float ks_pre[32];
    __shared__ float vs_pre[32];
    const int n = blockIdx.x, t = threadIdx.x;

    unsigned short* kfb = (unsigned short*)((char*)ws + KFB_BYTE);
    unsigned short* qfb = (unsigned short*)((char*)ws + QFB_BYTE);
    unsigned short* gwp = (unsigned short*)((char*)ws + GWBT_BYTE);
    unsigned short* vtb = (unsigned short*)((char*)ws + VTB_BYTE);

    mvn[t] = mv[n * 256 + t];
    if (t < 128) sn[t] = s[n * 128 + t];
    __syncthreads();

    // q_s pre-rope: 256 outputs
    {
        const float4* w = (const float4*)(q_w_s + t * 128);
        const float4* sv = (const float4*)sn;
        float acc = 0.f;
        #pragma unroll
        for (int c4 = 0; c4 < 32; ++c4) {
            float4 wv = w[c4], x = sv[c4];
            acc += wv.x * x.x + wv.y * x.y + wv.z * x.z + wv.w * x.w;
        }
        qs_pre[t] = acc;
    }
    if (t < 64) {
        const float* wb = (t < 32) ? (k_w_s + t * 128) : (v_w_s + (t - 32) * 128);
        const float4* w = (const float4*)wb;
        const float4* sv = (const float4*)sn;
        float acc = 0.f;
        #pragma unroll
        for (int c4 = 0; c4 < 32; ++c4) {
            float4 wv = w[c4], x = sv[c4];
            acc += wv.x * x.x + wv.y * x.y + wv.z * x.z + wv.w * x.w;
        }
        if (t < 32) ks_pre[t] = acc; else vs_pre[t - 32] = acc;
    }
    // q_mv inner blades -> qfb[q][h][d], d = c*8+j in [0,32)
    {
        int o = t >> 3, j = t & 7;
        int bx = INNER_C[j], g = GRADE_C[bx];
        float acc = 0.f;
        #pragma unroll
        for (int i = 0; i < 16; ++i)
            acc += mvn[i * 16 + bx] * q_w_mv[(o * 16 + i) * 5 + g];
        int h = o >> 2, c = o & 3, d = c * 8 + j;
        qfb[n * 1024 + h * 64 + d] = f2bf(acc);
    }
    // zero-fill qfb cols j=8..15
    {
        int hp = 8 + (t >> 5), d = t & 31;
        qfb[n * 1024 + hp * 64 + d] = 0;
        qfb[n * 1024 + hp * 64 + 32 + d] = 0;
    }
    // k_mv inner -> kfb[n][d], d = t in [0,32)
    if (t < 32) {
        int bx = INNER_C[t & 7], g = GRADE_C[bx];
        float acc = 0.f;
        #pragma unroll
        for (int i = 0; i < 16; ++i)
            acc += mvn[i * 16 + bx] * k_w_mv[((t >> 3) * 16 + i) * 5 + g];
        kfb[n * 64 + t] = f2bf(acc);
    }
    // v_mv full 16 blades -> Vt[comp][n] bf16 (comp = (t-64) in [0,64))
    if (t >= 64 && t < 128) {
        int idx = t - 64, x = idx & 15, g = GRADE_C[x];
        float acc = 0.f;
        #pragma unroll
        for (int i = 0; i < 16; ++i)
            acc += mvn[i * 16 + x] * v_w_mv[((idx >> 4) * 16 + i) * 5 + g];
        vtb[idx * 1024 + n] = f2bf(acc);
    }
    __syncthreads();

    // rope(q_s) -> qfb[q][h][32+dd]
    {
        int h = t >> 5, dd = t & 31, i = dd >> 1;
        float freq = exp2f(-0.75f * (float)i);
        float ang = (float)n * freq;
        float cv = cosf(ang), sv = sinf(ang);
        float x1 = qs_pre[h * 32 + 2 * i], x2 = qs_pre[h * 32 + 2 * i + 1];
        float val = ((dd & 1) == 0) ? (x1 * cv - x2 * sv) : (x1 * sv + x2 * cv);
        qfb[n * 1024 + h * 64 + 32 + dd] = f2bf(val);
    }
    // rope(k_s) -> kfb[n][32+dd]
    if (t < 32) {
        int i = t >> 1;
        float freq = exp2f(-0.75f * (float)i);
        float ang = (float)n * freq;
        float cv = cosf(ang), sv = sinf(ang);
        float x1 = ks_pre[2 * i], x2 = ks_pre[2 * i + 1];
        float val = ((t & 1) == 0) ? (x1 * cv - x2 * sv) : (x1 * sv + x2 * cv);
        kfb[n * 64 + 32 + t] = f2bf(val);
    }
    // v_s -> Vt rows 64..95
    if (t >= 32 && t < 64) vtb[(64 + t - 32) * 1024 + n] = f2bf(vs_pre[t - 32]);

    // folded LN constants + PERMUTED gwBT (block 0 only)
    if (n == 0) {
        if (t < 128) {
            // physical channel t -> MFMA k-slot position (matches kbias z-load pattern)
            int cb = t >> 5, r = t & 31;
            int lg, e;
            if (r < 16) { lg = r >> 2; e = r & 3; }
            else        { lg = (r - 16) >> 2; e = 4 + (r & 3); }
            int pos = cb * 32 + lg * 8 + e;
            float g = ln_g[t];
            #pragma unroll
            for (int j = 0; j < 8; ++j)
                gwp[j * 128 + pos] = f2bf(g * bias_w[t * 8 + j]);
            gwp[8 * 128 + pos] = 0x3F80;  // ones row -> channel sum
            #pragma unroll
            for (int j = 9; j < 16; ++j) gwp[j * 128 + pos] = 0;
        }
        if (t >= 128 && t < 136) {
            int h = t - 128;
            float gh = 0.f, ch = 0.f;
            for (int c = 0; c < 128; ++c) {
                gh += ln_g[c] * bias_w[c * 8 + h];
                ch += ln_b[c] * bias_w[c * 8 + h];
            }
            ws[OFF_GH + h] = gh;
            ws[OFF_GH + 8 + h] = ch;
        }
    }
}

// ---------------- kernel A: MFMA fused LN-bias + logits -> s (bf16) ----------------
__global__ __launch_bounds__(256, 4) void kbias(
    const float* __restrict__ z, float* __restrict__ ws)
{
    __shared__ float d1[128][17];   // dg cols 0-7, sum col 8
    __shared__ float d2[128][17];   // dq cols 0-7
    __shared__ float ssq[128];
    const int blk = blockIdx.x;
    const int q = blk >> 3, kblk = blk & 7;
    const int t = threadIdx.x, w = t >> 6, l = t & 63;
    const int lm = l & 15, lg = l >> 4;

    bf16x8 B1[4], B2[2];
    #pragma unroll
    for (int ks = 0; ks < 4; ++ks)
        B1[ks] = *(const bf16x8*)((const char*)ws + GWBT_BYTE + (lm * 128 + ks * 32 + lg * 8) * 2);
    #pragma unroll
    for (int ds = 0; ds < 2; ++ds)
        B2[ds] = *(const bf16x8*)((const char*)ws + QFB_BYTE + ((size_t)q * 1024 + lm * 64 + ds * 32 + lg * 8) * 2);

    #pragma unroll
    for (int mi = 0; mi < 2; ++mi) {
        const int mt = w * 2 + mi;
        const int krow = kblk * 128 + mt * 16 + lm;
        // fully-coalesced: lanes lg=0..3 cover one 64B segment per row
        const float* zr = z + ((size_t)q * 1024 + krow) * 128 + lg * 4;
        float4 za[4], zb[4];
        #pragma unroll
        for (int ks = 0; ks < 4; ++ks) {
            za[ks] = *(const float4*)(zr + ks * 32);        // c = ks*32 + lg*4 + e
            zb[ks] = *(const float4*)(zr + ks * 32 + 16);   // c = ks*32 + 16 + lg*4 + e
        }
        bf16x8 A2[2];
        #pragma unroll
        for (int ds = 0; ds < 2; ++ds)
            A2[ds] = *(const bf16x8*)((const char*)ws + KFB_BYTE + ((size_t)krow * 64 + ds * 32 + lg * 8) * 2);

        f32x4 acc1 = {0.f, 0.f, 0.f, 0.f};
        f32x4 acc2 = {0.f, 0.f, 0.f, 0.f};
        float sq = 0.f;
        #pragma unroll
        for (int ks = 0; ks < 4; ++ks) {
            float xs[8] = {za[ks].x, za[ks].y, za[ks].z, za[ks].w,
                           zb[ks].x, zb[ks].y, zb[ks].z, zb[ks].w};
            #pragma unroll
            for (int e = 0; e < 8; ++e) sq = __builtin_fmaf(xs[e], xs[e], sq);
            u32x4 au;
            au[0] = pk2(xs[0], xs[1]); au[1] = pk2(xs[2], xs[3]);
            au[2] = pk2(xs[4], xs[5]); au[3] = pk2(xs[6], xs[7]);
            bf16x8 af = __builtin_bit_cast(bf16x8, au);
            acc1 = __builtin_amdgcn_mfma_f32_16x16x32_bf16(af, B1[ks], acc1, 0, 0, 0);
        }
        acc2 = __builtin_amdgcn_mfma_f32_16x16x32_bf16(A2[0], B2[0], acc2, 0, 0, 0);
        acc2 = __builtin_amdgcn_mfma_f32_16x16x32_bf16(A2[1], B2[1], acc2, 0, 0, 0);

        sq += __shfl_xor(sq, 16);
        sq += __shfl_xor(sq, 32);
        if (lg == 0) ssq[mt * 16 + lm] = sq;

        #pragma unroll
        for (int r = 0; r < 4; ++r) {
            int row = mt * 16 + lg * 4 + r;
            d1[row][lm] = acc1[r];
            d2[row][lm] = acc2[r];
        }
    }
    __syncthreads();

    {
        const int r = t >> 1, hb = t & 1;
        float sum = d1[r][8];
        float sq = ssq[r];
        float mean = sum * (1.f / 128.f);
        float var = sq * (1.f / 128.f) - mean * mean;
        float rs = rsqrtf(var + 1e-5f);
        unsigned short u[4];
        #pragma unroll
        for (int j = 0; j < 4; ++j) {
            int h = hb * 4 + j;
            float bias = rs * (d1[r][h] - mean * ws[OFF_GH + h]) + ws[OFF_GH + 8 + h];
            u[j] = f2bf(d2[r][h] * 0.125f + bias);
        }
        uint2 pk;
        pk.x = (unsigned)u[0] | ((unsigned)u[1] << 16);
        pk.y = (unsigned)u[2] | ((unsigned)u[3] << 16);
        unsigned short* sb = (unsigned short*)((char*)ws + SB_BYTE);
        *(uint2*)(sb + ((size_t)q * 1024 + kblk * 128 + r) * 8 + hb * 4) = pk;
    }
}

// ---------------- kernel B: softmax + MFMA PV + output projections ----------------
__global__ __launch_bounds__(256) void kattn(
    const float* __restrict__ ws,
    const float* __restrict__ out_w_mv, const float* __restrict__ out_w_s,
    float* __restrict__ d_out)
{
    __shared__ __align__(16) unsigned int Pb[16 * 512];  // bf16 [16][1024], XOR-swizzled, rows 8-15 garbage
    __shared__ float inv_l[8];
    __shared__ float o_sh[8 * 96];                       // [h][comp]
    const int q = blockIdx.x, t = threadIdx.x;

    const unsigned short* sb =
        (const unsigned short*)((const char*)ws + SB_BYTE) + (size_t)q * 8192;
    // load s + transpose to Pb[h][k] (u32 = 2 adjacent k), swizzle word ^= h<<2
    #pragma unroll
    for (int it = 0; it < 2; ++it) {
        int wd = it * 256 + t;
        uint4 r0 = *(const uint4*)(sb + (size_t)wd * 16);
        uint4 r1 = *(const uint4*)(sb + (size_t)wd * 16 + 8);
        Pb[0 * 512 + (wd ^ (0 << 2))] = (r0.x & 0xffffu) | (r1.x << 16);
        Pb[1 * 512 + (wd ^ (1 << 2))] = (r0.x >> 16) | (r1.x & 0xffff0000u);
        Pb[2 * 512 + (wd ^ (2 << 2))] = (r0.y & 0xffffu) | (r1.y << 16);
        Pb[3 * 512 + (wd ^ (3 << 2))] = (r0.y >> 16) | (r1.y & 0xffff0000u);
        Pb[4 * 512 + (wd ^ (4 << 2))] = (r0.z & 0xffffu) | (r1.z << 16);
        Pb[5 * 512 + (wd ^ (5 << 2))] = (r0.z >> 16) | (r1.z & 0xffff0000u);
        Pb[6 * 512 + (wd ^ (6 << 2))] = (r0.w & 0xffffu) | (r1.w << 16);
        Pb[7 * 512 + (wd ^ (7 << 2))] = (r0.w >> 16) | (r1.w & 0xffff0000u);
    }
    __syncthreads();

    // softmax per head, in place (bf16)
    const int h = t >> 5, e = t & 31;
    const int hx = (h & 7) << 2;
    unsigned int* Ph = &Pb[h * 512];
    float m = -1e30f;
    #pragma unroll
    for (int j = 0; j < 16; ++j) {
        unsigned int v = Ph[(e + j * 32) ^ hx];
        m = fmaxf(m, fmaxf(bflo(v), bfhi(v)));
    }
    #pragma unroll
    for (int d = 16; d >= 1; d >>= 1) m = fmaxf(m, __shfl_xor(m, d));
    float lsum = 0.f;
    #pragma unroll
    for (int j = 0; j < 16; ++j) {
        int idx = (e + j * 32) ^ hx;
        unsigned int v = Ph[idx];
        float p0 = __expf(bflo(v) - m);
        float p1 = __expf(bfhi(v) - m);
        lsum += p0 + p1;
        Ph[idx] = pk2(p0, p1);
    }
    #pragma unroll
    for (int d = 16; d >= 1; d >>= 1) lsum += __shfl_xor(lsum, d);
    if (e == 0) inv_l[h] = 1.f / lsum;
    __syncthreads();

    // PV via MFMA: C[comp][head] = Vt(96x1024) . P^T(1024x16)
    const int wv = t >> 6, l = t & 63, lm = l & 15, lg = l >> 4;
    const unsigned short* vtb = (const unsigned short*)((const char*)ws + VTB_BYTE);
    const char* PbB = (const char*)Pb;
    const int nmt = (wv < 2) ? 2 : 1;
    for (int ii = 0; ii < nmt; ++ii) {
        int mt = wv + ii * 4;
        f32x4 acc = {0.f, 0.f, 0.f, 0.f};
        #pragma unroll 8
        for (int ks = 0; ks < 32; ++ks) {
            bf16x8 a = *(const bf16x8*)(vtb + (size_t)(mt * 16 + lm) * 1024 + ks * 32 + lg * 8);
            bf16x8 b = *(const bf16x8*)(PbB + lm * 2048 + ((ks * 64 + lg * 16) ^ ((lm & 7) << 4)));
            acc = __builtin_amdgcn_mfma_f32_16x16x32_bf16(a, b, acc, 0, 0, 0);
        }
        if (lm < 8) {
            float il = inv_l[lm];
            #pragma unroll
            for (int r = 0; r < 4; ++r)
                o_sh[lm * 96 + mt * 16 + lg * 4 + r] = acc[r] * il;
        }
    }
    __syncthreads();

    // out_mv: 256 outputs
    {
        int o2 = t >> 4, b = t & 15, g = GRADE_C[b];
        float acc = 0.f;
        #pragma unroll
        for (int i = 0; i < 32; ++i)
            acc += o_sh[(i >> 2) * 96 + (i & 3) * 16 + b] *
                   out_w_mv[(o2 * 32 + i) * 5 + g];
        d_out[(q * 16 + o2) * 16 + b] = acc;
    }
    // out_s: 128 outputs
    if (t < 128) {
        const float* wv2 = out_w_s + t * 256;
        float acc = 0.f;
        #pragma unroll 4
        for (int c = 0; c < 256; ++c)
            acc += o_sh[(c >> 5) * 96 + 64 + (c & 31)] * wv2[c];
        d_out[262144 + q * 128 + t] = acc;
    }
}

// ---------------- launch ----------------
extern "C" void kernel_launch(void* const* d_in, const int* in_sizes, int n_in,
                              void* d_out, int out_size, void* d_ws, size_t ws_size,
                              hipStream_t stream) {
    (void)in_sizes; (void)n_in; (void)out_size; (void)ws_size;
    const float* mv       = (const float*)d_in[0];
    const float* s        = (const float*)d_in[1];
    const float* z        = (const float*)d_in[2];
    const float* q_w_mv   = (const float*)d_in[3];
    const float* q_w_s    = (const float*)d_in[4];
    const float* k_w_mv   = (const float*)d_in[5];
    const float* k_w_s    = (const float*)d_in[6];
    const float* v_w_mv   = (const float*)d_in[7];
    const float* v_w_s    = (const float*)d_in[8];
    const float* out_w_mv = (const float*)d_in[9];
    const float* out_w_s  = (const float*)d_in[10];
    const float* ln_g     = (const float*)d_in[11];
    const float* ln_b     = (const float*)d_in[12];
    const float* bias_w   = (const float*)d_in[13];
    float* ws  = (float*)d_ws;
    float* out = (float*)d_out;

    kproj<<<1024, 256, 0, stream>>>(mv, s, q_w_mv, q_w_s, k_w_mv, k_w_s,
                                    v_w_mv, v_w_s, ln_g, ln_b, bias_w, ws);
    kbias<<<8192, 256, 0, stream>>>(z, ws);
    kattn<<<1024, 256, 0, stream>>>(ws, out_w_mv, out_w_s, out);
}

// Round 5
// 186.880 us; speedup vs baseline: 3.0821x; 1.0390x over previous
//
#include <hip/hip_runtime.h>
#include <hip/hip_bf16.h>

// ---------------- constants ----------------
__device__ __constant__ int GRADE_C[16] = {0,1,1,1,1,2,2,2,2,2,2,3,3,3,3,4};
__device__ __constant__ int INNER_C[8]  = {0,2,3,4,8,9,10,14};

// workspace layout (bytes unless noted)
#define OFF_GH    0         // float idx 0..15: Gh[8], Ch[8]
#define GWBT_BYTE 4096      // gwBT[j(16)][c(128)] bf16, k-slot PERMUTED : 4 KB
#define KFB_BYTE  16384     // kf[n][64] bf16                            : 128 KB
#define VTB_BYTE  262144    // Vt[comp(96)][n(1024)] bf16                : 192 KB
#define QFB_BYTE  524288    // qfb[q][j(16)][d(64)] bf16                 : 2 MB
#define SB_BYTE   3145728   // s[q][k][h(8)] bf16                        : 16 MB

typedef __attribute__((ext_vector_type(8))) short bf16x8;
typedef __attribute__((ext_vector_type(4))) float f32x4;
typedef __attribute__((ext_vector_type(4))) unsigned int u32x4;

static __device__ __forceinline__ unsigned short f2bf(float f) {
    unsigned int u = __float_as_uint(f);
    u = u + 0x7fffu + ((u >> 16) & 1u);
    return (unsigned short)(u >> 16);
}
static __device__ __forceinline__ unsigned pk2(float lo, float hi) {
    return (unsigned)f2bf(lo) | ((unsigned)f2bf(hi) << 16);
}
static __device__ __forceinline__ unsigned cvtpk(float lo, float hi) {
    __hip_bfloat162 c = __float22bfloat162_rn(make_float2(lo, hi));
    unsigned u;
    __builtin_memcpy(&u, &c, 4);
    return u;
}
static __device__ __forceinline__ float bflo(unsigned int u) {
    return __uint_as_float(u << 16);
}
static __device__ __forceinline__ float bfhi(unsigned int u) {
    return __uint_as_float(u & 0xffff0000u);
}

// ---------------- kernel P: projections ----------------
__global__ __launch_bounds__(256) void kproj(
    const float* __restrict__ mv, const float* __restrict__ s,
    const float* __restrict__ q_w_mv, const float* __restrict__ q_w_s,
    const float* __restrict__ k_w_mv, const float* __restrict__ k_w_s,
    const float* __restrict__ v_w_mv, const float* __restrict__ v_w_s,
    const float* __restrict__ ln_g, const float* __restrict__ ln_b,
    const float* __restrict__ bias_w, float* __restrict__ ws)
{
    __shared__ __align__(16) float mvn[256];
    __shared__ __align__(16) float sn[128];
    __shared__ float qs_pre[256];
    __shared__ float ks_pre[32];
    __shared__ float vs_pre[32];
    const int n = blockIdx.x, t = threadIdx.x;

    unsigned short* kfb = (unsigned short*)((char*)ws + KFB_BYTE);
    unsigned short* qfb = (unsigned short*)((char*)ws + QFB_BYTE);
    unsigned short* gwp = (unsigned short*)((char*)ws + GWBT_BYTE);
    unsigned short* vtb = (unsigned short*)((char*)ws + VTB_BYTE);

    mvn[t] = mv[n * 256 + t];
    if (t < 128) sn[t] = s[n * 128 + t];
    __syncthreads();

    // q_s pre-rope: 256 outputs
    {
        const float4* w = (const float4*)(q_w_s + t * 128);
        const float4* sv = (const float4*)sn;
        float acc = 0.f;
        #pragma unroll
        for (int c4 = 0; c4 < 32; ++c4) {
            float4 wv = w[c4], x = sv[c4];
            acc += wv.x * x.x + wv.y * x.y + wv.z * x.z + wv.w * x.w;
        }
        qs_pre[t] = acc;
    }
    if (t < 64) {
        const float* wb = (t < 32) ? (k_w_s + t * 128) : (v_w_s + (t - 32) * 128);
        const float4* w = (const float4*)wb;
        const float4* sv = (const float4*)sn;
        float acc = 0.f;
        #pragma unroll
        for (int c4 = 0; c4 < 32; ++c4) {
            float4 wv = w[c4], x = sv[c4];
            acc += wv.x * x.x + wv.y * x.y + wv.z * x.z + wv.w * x.w;
        }
        if (t < 32) ks_pre[t] = acc; else vs_pre[t - 32] = acc;
    }
    // q_mv inner blades -> qfb[q][h][d], d = c*8+j in [0,32)
    {
        int o = t >> 3, j = t & 7;
        int bx = INNER_C[j], g = GRADE_C[bx];
        float acc = 0.f;
        #pragma unroll
        for (int i = 0; i < 16; ++i)
            acc += mvn[i * 16 + bx] * q_w_mv[(o * 16 + i) * 5 + g];
        int h = o >> 2, c = o & 3, d = c * 8 + j;
        qfb[n * 1024 + h * 64 + d] = f2bf(acc);
    }
    // zero-fill qfb cols j=8..15
    {
        int hp = 8 + (t >> 5), d = t & 31;
        qfb[n * 1024 + hp * 64 + d] = 0;
        qfb[n * 1024 + hp * 64 + 32 + d] = 0;
    }
    // k_mv inner -> kfb[n][d], d = t in [0,32)
    if (t < 32) {
        int bx = INNER_C[t & 7], g = GRADE_C[bx];
        float acc = 0.f;
        #pragma unroll
        for (int i = 0; i < 16; ++i)
            acc += mvn[i * 16 + bx] * k_w_mv[((t >> 3) * 16 + i) * 5 + g];
        kfb[n * 64 + t] = f2bf(acc);
    }
    // v_mv full 16 blades -> Vt[comp][n] bf16 (comp = (t-64) in [0,64))
    if (t >= 64 && t < 128) {
        int idx = t - 64, x = idx & 15, g = GRADE_C[x];
        float acc = 0.f;
        #pragma unroll
        for (int i = 0; i < 16; ++i)
            acc += mvn[i * 16 + x] * v_w_mv[((idx >> 4) * 16 + i) * 5 + g];
        vtb[idx * 1024 + n] = f2bf(acc);
    }
    __syncthreads();

    // rope(q_s) -> qfb[q][h][32+dd]
    {
        int h = t >> 5, dd = t & 31, i = dd >> 1;
        float freq = exp2f(-0.75f * (float)i);
        float ang = (float)n * freq;
        float cv = cosf(ang), sv = sinf(ang);
        float x1 = qs_pre[h * 32 + 2 * i], x2 = qs_pre[h * 32 + 2 * i + 1];
        float val = ((dd & 1) == 0) ? (x1 * cv - x2 * sv) : (x1 * sv + x2 * cv);
        qfb[n * 1024 + h * 64 + 32 + dd] = f2bf(val);
    }
    // rope(k_s) -> kfb[n][32+dd]
    if (t < 32) {
        int i = t >> 1;
        float freq = exp2f(-0.75f * (float)i);
        float ang = (float)n * freq;
        float cv = cosf(ang), sv = sinf(ang);
        float x1 = ks_pre[2 * i], x2 = ks_pre[2 * i + 1];
        float val = ((t & 1) == 0) ? (x1 * cv - x2 * sv) : (x1 * sv + x2 * cv);
        kfb[n * 64 + 32 + t] = f2bf(val);
    }
    // v_s -> Vt rows 64..95
    if (t >= 32 && t < 64) vtb[(64 + t - 32) * 1024 + n] = f2bf(vs_pre[t - 32]);

    // folded LN constants + PERMUTED gwBT (block 0 only)
    if (n == 0) {
        if (t < 128) {
            // physical channel t -> MFMA k-slot position (matches kbias z-load pattern)
            int cb = t >> 5, r = t & 31;
            int lg, e;
            if (r < 16) { lg = r >> 2; e = r & 3; }
            else        { lg = (r - 16) >> 2; e = 4 + (r & 3); }
            int pos = cb * 32 + lg * 8 + e;
            float g = ln_g[t];
            #pragma unroll
            for (int j = 0; j < 8; ++j)
                gwp[j * 128 + pos] = f2bf(g * bias_w[t * 8 + j]);
            gwp[8 * 128 + pos] = 0x3F80;  // ones row -> channel sum
            #pragma unroll
            for (int j = 9; j < 16; ++j) gwp[j * 128 + pos] = 0;
        }
        if (t >= 128 && t < 136) {
            int h = t - 128;
            float gh = 0.f, ch = 0.f;
            for (int c = 0; c < 128; ++c) {
                gh += ln_g[c] * bias_w[c * 8 + h];
                ch += ln_b[c] * bias_w[c * 8 + h];
            }
            ws[OFF_GH + h] = gh;
            ws[OFF_GH + 8 + h] = ch;
        }
    }
}

// ---------------- kernel A: MFMA fused LN-bias + logits -> s (bf16) ----------------
__global__ __launch_bounds__(256, 4) void kbias(
    const float* __restrict__ z, float* __restrict__ ws)
{
    __shared__ float d1[128][17];   // dg cols 0-7, sum col 8
    __shared__ float d2[128][17];   // dq cols 0-7
    __shared__ float ssq[128];
    const int blk = blockIdx.x;
    const int q = blk >> 3, kblk = blk & 7;
    const int t = threadIdx.x, w = t >> 6, l = t & 63;
    const int lm = l & 15, lg = l >> 4;

    bf16x8 B1[4], B2[2];
    #pragma unroll
    for (int ks = 0; ks < 4; ++ks)
        B1[ks] = *(const bf16x8*)((const char*)ws + GWBT_BYTE + (lm * 128 + ks * 32 + lg * 8) * 2);
    #pragma unroll
    for (int ds = 0; ds < 2; ++ds)
        B2[ds] = *(const bf16x8*)((const char*)ws + QFB_BYTE + ((size_t)q * 1024 + lm * 64 + ds * 32 + lg * 8) * 2);

    // prefetch z for BOTH m-tiles up front (max HBM MLP)
    float4 za[2][4], zb[2][4];
    #pragma unroll
    for (int mi = 0; mi < 2; ++mi) {
        const int krow = kblk * 128 + (w * 2 + mi) * 16 + lm;
        const float* zr = z + ((size_t)q * 1024 + krow) * 128 + lg * 4;
        #pragma unroll
        for (int ks = 0; ks < 4; ++ks) {
            za[mi][ks] = *(const float4*)(zr + ks * 32);        // c = ks*32 + lg*4 + e
            zb[mi][ks] = *(const float4*)(zr + ks * 32 + 16);   // c = ks*32 + 16 + lg*4 + e
        }
    }

    #pragma unroll
    for (int mi = 0; mi < 2; ++mi) {
        const int mt = w * 2 + mi;
        const int krow = kblk * 128 + mt * 16 + lm;
        bf16x8 A2[2];
        #pragma unroll
        for (int ds = 0; ds < 2; ++ds)
            A2[ds] = *(const bf16x8*)((const char*)ws + KFB_BYTE + ((size_t)krow * 64 + ds * 32 + lg * 8) * 2);

        f32x4 acc1 = {0.f, 0.f, 0.f, 0.f};
        f32x4 acc2 = {0.f, 0.f, 0.f, 0.f};
        float sq = 0.f;
        #pragma unroll
        for (int ks = 0; ks < 4; ++ks) {
            float4 A = za[mi][ks], Bv = zb[mi][ks];
            sq = __builtin_fmaf(A.x, A.x, sq);  sq = __builtin_fmaf(A.y, A.y, sq);
            sq = __builtin_fmaf(A.z, A.z, sq);  sq = __builtin_fmaf(A.w, A.w, sq);
            sq = __builtin_fmaf(Bv.x, Bv.x, sq); sq = __builtin_fmaf(Bv.y, Bv.y, sq);
            sq = __builtin_fmaf(Bv.z, Bv.z, sq); sq = __builtin_fmaf(Bv.w, Bv.w, sq);
            u32x4 au;
            au[0] = cvtpk(A.x, A.y);   au[1] = cvtpk(A.z, A.w);
            au[2] = cvtpk(Bv.x, Bv.y); au[3] = cvtpk(Bv.z, Bv.w);
            bf16x8 af = __builtin_bit_cast(bf16x8, au);
            acc1 = __builtin_amdgcn_mfma_f32_16x16x32_bf16(af, B1[ks], acc1, 0, 0, 0);
        }
        acc2 = __builtin_amdgcn_mfma_f32_16x16x32_bf16(A2[0], B2[0], acc2, 0, 0, 0);
        acc2 = __builtin_amdgcn_mfma_f32_16x16x32_bf16(A2[1], B2[1], acc2, 0, 0, 0);

        sq += __shfl_xor(sq, 16);
        sq += __shfl_xor(sq, 32);
        if (lg == 0) ssq[mt * 16 + lm] = sq;

        #pragma unroll
        for (int r = 0; r < 4; ++r) {
            int row = mt * 16 + lg * 4 + r;
            d1[row][lm] = acc1[r];
            d2[row][lm] = acc2[r];
        }
    }
    __syncthreads();

    {
        const int r = t >> 1, hb = t & 1;
        float sum = d1[r][8];
        float sq = ssq[r];
        float mean = sum * (1.f / 128.f);
        float var = sq * (1.f / 128.f) - mean * mean;
        float rs = rsqrtf(var + 1e-5f);
        unsigned short u[4];
        #pragma unroll
        for (int j = 0; j < 4; ++j) {
            int h = hb * 4 + j;
            float bias = rs * (d1[r][h] - mean * ws[OFF_GH + h]) + ws[OFF_GH + 8 + h];
            u[j] = f2bf(d2[r][h] * 0.125f + bias);
        }
        uint2 pk;
        pk.x = (unsigned)u[0] | ((unsigned)u[1] << 16);
        pk.y = (unsigned)u[2] | ((unsigned)u[3] << 16);
        unsigned short* sb = (unsigned short*)((char*)ws + SB_BYTE);
        *(uint2*)(sb + ((size_t)q * 1024 + kblk * 128 + r) * 8 + hb * 4) = pk;
    }
}

// ---------------- kernel B: softmax + MFMA PV + output projections ----------------
__global__ __launch_bounds__(512) void kattn(
    const float* __restrict__ ws,
    const float* __restrict__ out_w_mv, const float* __restrict__ out_w_s,
    float* __restrict__ d_out)
{
    __shared__ __align__(16) unsigned int Pb[16 * 512];  // bf16 [16][1024], XOR-swizzled, rows 8-15 garbage
    __shared__ float inv_l[8];
    __shared__ float o_sh[8 * 96];                       // [h][comp]
    const int q = blockIdx.x, t = threadIdx.x;

    const unsigned short* sb =
        (const unsigned short*)((const char*)ws + SB_BYTE) + (size_t)q * 8192;
    // load s + transpose to Pb[h][k] (u32 = 2 adjacent k), swizzle word ^= h<<2
    {
        int wd = t;   // 0..511
        uint4 r0 = *(const uint4*)(sb + (size_t)wd * 16);
        uint4 r1 = *(const uint4*)(sb + (size_t)wd * 16 + 8);
        Pb[0 * 512 + (wd ^ (0 << 2))] = (r0.x & 0xffffu) | (r1.x << 16);
        Pb[1 * 512 + (wd ^ (1 << 2))] = (r0.x >> 16) | (r1.x & 0xffff0000u);
        Pb[2 * 512 + (wd ^ (2 << 2))] = (r0.y & 0xffffu) | (r1.y << 16);
        Pb[3 * 512 + (wd ^ (3 << 2))] = (r0.y >> 16) | (r1.y & 0xffff0000u);
        Pb[4 * 512 + (wd ^ (4 << 2))] = (r0.z & 0xffffu) | (r1.z << 16);
        Pb[5 * 512 + (wd ^ (5 << 2))] = (r0.z >> 16) | (r1.z & 0xffff0000u);
        Pb[6 * 512 + (wd ^ (6 << 2))] = (r0.w & 0xffffu) | (r1.w << 16);
        Pb[7 * 512 + (wd ^ (7 << 2))] = (r0.w >> 16) | (r1.w & 0xffff0000u);
    }
    __syncthreads();

    // softmax per head, in place (bf16): one wave per head, 64 lanes x 8 words
    const int h = t >> 6, e = t & 63;
    const int hx = (h & 7) << 2;
    unsigned int* Ph = &Pb[h * 512];
    float m = -1e30f;
    #pragma unroll
    for (int j = 0; j < 8; ++j) {
        unsigned int v = Ph[(e + j * 64) ^ hx];
        m = fmaxf(m, fmaxf(bflo(v), bfhi(v)));
    }
    #pragma unroll
    for (int d = 32; d >= 1; d >>= 1) m = fmaxf(m, __shfl_xor(m, d));
    float lsum = 0.f;
    #pragma unroll
    for (int j = 0; j < 8; ++j) {
        int idx = (e + j * 64) ^ hx;
        unsigned int v = Ph[idx];
        float p0 = __expf(bflo(v) - m);
        float p1 = __expf(bfhi(v) - m);
        lsum += p0 + p1;
        Ph[idx] = pk2(p0, p1);
    }
    #pragma unroll
    for (int d = 32; d >= 1; d >>= 1) lsum += __shfl_xor(lsum, d);
    if (e == 0) inv_l[h] = 1.f / lsum;
    __syncthreads();

    // PV via MFMA: C[comp][head] = Vt(96x1024) . P^T(1024x16); waves 0..5, one m-tile each
    const int wv = t >> 6, l = t & 63, lm = l & 15, lg = l >> 4;
    const unsigned short* vtb = (const unsigned short*)((const char*)ws + VTB_BYTE);
    const char* PbB = (const char*)Pb;
    if (wv < 6) {
        int mt = wv;
        f32x4 acc = {0.f, 0.f, 0.f, 0.f};
        #pragma unroll 8
        for (int ks = 0; ks < 32; ++ks) {
            bf16x8 a = *(const bf16x8*)(vtb + (size_t)(mt * 16 + lm) * 1024 + ks * 32 + lg * 8);
            bf16x8 b = *(const bf16x8*)(PbB + lm * 2048 + ((ks * 64 + lg * 16) ^ ((lm & 7) << 4)));
            acc = __builtin_amdgcn_mfma_f32_16x16x32_bf16(a, b, acc, 0, 0, 0);
        }
        if (lm < 8) {
            float il = inv_l[lm];
            #pragma unroll
            for (int r = 0; r < 4; ++r)
                o_sh[lm * 96 + mt * 16 + lg * 4 + r] = acc[r] * il;
        }
    }
    __syncthreads();

    // out_mv: 256 outputs
    if (t < 256) {
        int o2 = t >> 4, b = t & 15, g = GRADE_C[b];
        float acc = 0.f;
        #pragma unroll
        for (int i = 0; i < 32; ++i)
            acc += o_sh[(i >> 2) * 96 + (i & 3) * 16 + b] *
                   out_w_mv[(o2 * 32 + i) * 5 + g];
        d_out[(q * 16 + o2) * 16 + b] = acc;
    }
    // out_s: 128 outputs
    if (t >= 256 && t < 384) {
        int tt = t - 256;
        const float* wv2 = out_w_s + tt * 256;
        float acc = 0.f;
        #pragma unroll 4
        for (int c = 0; c < 256; ++c)
            acc += o_sh[(c >> 5) * 96 + 64 + (c & 31)] * wv2[c];
        d_out[262144 + q * 128 + tt] = acc;
    }
}

// ---------------- launch ----------------
extern "C" void kernel_launch(void* const* d_in, const int* in_sizes, int n_in,
                              void* d_out, int out_size, void* d_ws, size_t ws_size,
                              hipStream_t stream) {
    (void)in_sizes; (void)n_in; (void)out_size; (void)ws_size;
    const float* mv       = (const float*)d_in[0];
    const float* s        = (const float*)d_in[1];
    const float* z        = (const float*)d_in[2];
    const float* q_w_mv   = (const float*)d_in[3];
    const float* q_w_s    = (const float*)d_in[4];
    const float* k_w_mv   = (const float*)d_in[5];
    const float* k_w_s    = (const float*)d_in[6];
    const float* v_w_mv   = (const float*)d_in[7];
    const float* v_w_s    = (const float*)d_in[8];
    const float* out_w_mv = (const float*)d_in[9];
    const float* out_w_s  = (const float*)d_in[10];
    const float* ln_g     = (const float*)d_in[11];
    const float* ln_b     = (const float*)d_in[12];
    const float* bias_w   = (const float*)d_in[13];
    float* ws  = (float*)d_ws;
    float* out = (float*)d_out;

    kproj<<<1024, 256, 0, stream>>>(mv, s, q_w_mv, q_w_s, k_w_mv, k_w_s,
                                    v_w_mv, v_w_s, ln_g, ln_b, bias_w, ws);
    kbias<<<8192, 256, 0, stream>>>(z, ws);
    kattn<<<1024, 512, 0, stream>>>(ws, out_w_mv, out_w_s, out);
}

// Round 6
// 178.120 us; speedup vs baseline: 3.2337x; 1.0492x over previous
//
#include <hip/hip_runtime.h>
#include <hip/hip_bf16.h>

// ---------------- constants ----------------
__device__ __constant__ int GRADE_C[16] = {0,1,1,1,1,2,2,2,2,2,2,3,3,3,3,4};
__device__ __constant__ int INNER_C[8]  = {0,2,3,4,8,9,10,14};

// workspace layout (bytes unless noted)
#define OFF_GH    0         // float idx 0..15: Gh[8], Ch[8]
#define GWBT_BYTE 4096      // gwBT[j(16)][c(128)] bf16, k-slot PERMUTED : 4 KB
#define KFB_BYTE  16384     // kf[n][64] bf16                            : 128 KB
#define VTB_BYTE  262144    // Vt[comp(96)][n(1024)] bf16                : 192 KB
#define QFB_BYTE  524288    // qfb[q][j(16)][d(64)] bf16                 : 2 MB

typedef __attribute__((ext_vector_type(8))) short bf16x8;
typedef __attribute__((ext_vector_type(4))) float f32x4;
typedef __attribute__((ext_vector_type(4))) unsigned int u32x4;

static __device__ __forceinline__ unsigned short f2bf(float f) {
    unsigned int u = __float_as_uint(f);
    u = u + 0x7fffu + ((u >> 16) & 1u);
    return (unsigned short)(u >> 16);
}
static __device__ __forceinline__ unsigned pk2(float lo, float hi) {
    return (unsigned)f2bf(lo) | ((unsigned)f2bf(hi) << 16);
}
static __device__ __forceinline__ unsigned cvtpk(float lo, float hi) {
    __hip_bfloat162 c = __float22bfloat162_rn(make_float2(lo, hi));
    unsigned u;
    __builtin_memcpy(&u, &c, 4);
    return u;
}
static __device__ __forceinline__ float bflo(unsigned int u) {
    return __uint_as_float(u << 16);
}
static __device__ __forceinline__ float bfhi(unsigned int u) {
    return __uint_as_float(u & 0xffff0000u);
}

// LDS-only barrier: drain LDS ops, raw s_barrier, leave VMEM loads in flight.
#define LDS_BAR() do { \
    asm volatile("s_waitcnt lgkmcnt(0)" ::: "memory"); \
    __builtin_amdgcn_s_barrier(); \
} while (0)

// ---------------- kernel P: projections ----------------
__global__ __launch_bounds__(256) void kproj(
    const float* __restrict__ mv, const float* __restrict__ s,
    const float* __restrict__ q_w_mv, const float* __restrict__ q_w_s,
    const float* __restrict__ k_w_mv, const float* __restrict__ k_w_s,
    const float* __restrict__ v_w_mv, const float* __restrict__ v_w_s,
    const float* __restrict__ ln_g, const float* __restrict__ ln_b,
    const float* __restrict__ bias_w, float* __restrict__ ws)
{
    __shared__ __align__(16) float mvn[256];
    __shared__ __align__(16) float sn[128];
    __shared__ float qs_pre[256];
    __shared__ float ks_pre[32];
    __shared__ float vs_pre[32];
    const int n = blockIdx.x, t = threadIdx.x;

    unsigned short* kfb = (unsigned short*)((char*)ws + KFB_BYTE);
    unsigned short* qfb = (unsigned short*)((char*)ws + QFB_BYTE);
    unsigned short* gwp = (unsigned short*)((char*)ws + GWBT_BYTE);
    unsigned short* vtb = (unsigned short*)((char*)ws + VTB_BYTE);

    mvn[t] = mv[n * 256 + t];
    if (t < 128) sn[t] = s[n * 128 + t];
    __syncthreads();

    // q_s pre-rope: 256 outputs
    {
        const float4* w = (const float4*)(q_w_s + t * 128);
        const float4* sv = (const float4*)sn;
        float acc = 0.f;
        #pragma unroll
        for (int c4 = 0; c4 < 32; ++c4) {
            float4 wv = w[c4], x = sv[c4];
            acc += wv.x * x.x + wv.y * x.y + wv.z * x.z + wv.w * x.w;
        }
        qs_pre[t] = acc;
    }
    if (t < 64) {
        const float* wb = (t < 32) ? (k_w_s + t * 128) : (v_w_s + (t - 32) * 128);
        const float4* w = (const float4*)wb;
        const float4* sv = (const float4*)sn;
        float acc = 0.f;
        #pragma unroll
        for (int c4 = 0; c4 < 32; ++c4) {
            float4 wv = w[c4], x = sv[c4];
            acc += wv.x * x.x + wv.y * x.y + wv.z * x.z + wv.w * x.w;
        }
        if (t < 32) ks_pre[t] = acc; else vs_pre[t - 32] = acc;
    }
    // q_mv inner blades -> qfb[q][h][d], d = c*8+j in [0,32)
    {
        int o = t >> 3, j = t & 7;
        int bx = INNER_C[j], g = GRADE_C[bx];
        float acc = 0.f;
        #pragma unroll
        for (int i = 0; i < 16; ++i)
            acc += mvn[i * 16 + bx] * q_w_mv[(o * 16 + i) * 5 + g];
        int h = o >> 2, c = o & 3, d = c * 8 + j;
        qfb[n * 1024 + h * 64 + d] = f2bf(acc);
    }
    // zero-fill qfb cols j=8..15
    {
        int hp = 8 + (t >> 5), d = t & 31;
        qfb[n * 1024 + hp * 64 + d] = 0;
        qfb[n * 1024 + hp * 64 + 32 + d] = 0;
    }
    // k_mv inner -> kfb[n][d], d = t in [0,32)
    if (t < 32) {
        int bx = INNER_C[t & 7], g = GRADE_C[bx];
        float acc = 0.f;
        #pragma unroll
        for (int i = 0; i < 16; ++i)
            acc += mvn[i * 16 + bx] * k_w_mv[((t >> 3) * 16 + i) * 5 + g];
        kfb[n * 64 + t] = f2bf(acc);
    }
    // v_mv full 16 blades -> Vt[comp][n] bf16 (comp = (t-64) in [0,64))
    if (t >= 64 && t < 128) {
        int idx = t - 64, x = idx & 15, g = GRADE_C[x];
        float acc = 0.f;
        #pragma unroll
        for (int i = 0; i < 16; ++i)
            acc += mvn[i * 16 + x] * v_w_mv[((idx >> 4) * 16 + i) * 5 + g];
        vtb[idx * 1024 + n] = f2bf(acc);
    }
    __syncthreads();

    // rope(q_s) -> qfb[q][h][32+dd]
    {
        int h = t >> 5, dd = t & 31, i = dd >> 1;
        float freq = exp2f(-0.75f * (float)i);
        float ang = (float)n * freq;
        float cv = cosf(ang), sv = sinf(ang);
        float x1 = qs_pre[h * 32 + 2 * i], x2 = qs_pre[h * 32 + 2 * i + 1];
        float val = ((dd & 1) == 0) ? (x1 * cv - x2 * sv) : (x1 * sv + x2 * cv);
        qfb[n * 1024 + h * 64 + 32 + dd] = f2bf(val);
    }
    // rope(k_s) -> kfb[n][32+dd]
    if (t < 32) {
        int i = t >> 1;
        float freq = exp2f(-0.75f * (float)i);
        float ang = (float)n * freq;
        float cv = cosf(ang), sv = sinf(ang);
        float x1 = ks_pre[2 * i], x2 = ks_pre[2 * i + 1];
        float val = ((t & 1) == 0) ? (x1 * cv - x2 * sv) : (x1 * sv + x2 * cv);
        kfb[n * 64 + 32 + t] = f2bf(val);
    }
    // v_s -> Vt rows 64..95
    if (t >= 32 && t < 64) vtb[(64 + t - 32) * 1024 + n] = f2bf(vs_pre[t - 32]);

    // folded LN constants + PERMUTED gwBT (block 0 only)
    if (n == 0) {
        if (t < 128) {
            // physical channel t -> MFMA k-slot position (matches kfused z-load pattern)
            int cb = t >> 5, r = t & 31;
            int lg, e;
            if (r < 16) { lg = r >> 2; e = r & 3; }
            else        { lg = (r - 16) >> 2; e = 4 + (r & 3); }
            int pos = cb * 32 + lg * 8 + e;
            float g = ln_g[t];
            #pragma unroll
            for (int j = 0; j < 8; ++j)
                gwp[j * 128 + pos] = f2bf(g * bias_w[t * 8 + j]);
            gwp[8 * 128 + pos] = 0x3F80;  // ones row -> channel sum
            #pragma unroll
            for (int j = 9; j < 16; ++j) gwp[j * 128 + pos] = 0;
        }
        if (t >= 128 && t < 136) {
            int h = t - 128;
            float gh = 0.f, ch = 0.f;
            for (int c = 0; c < 128; ++c) {
                gh += ln_g[c] * bias_w[c * 8 + h];
                ch += ln_b[c] * bias_w[c * 8 + h];
            }
            ws[OFF_GH + h] = gh;
            ws[OFF_GH + 8 + h] = ch;
        }
    }
}

// ---------------- kernel F: fused LN-bias + logits + softmax + PV + out-proj ----------------
// One block per q. 8 k-block iterations; finalize(prev) hidden under z prefetch
// via raw-barrier (lgkmcnt-only) so z loads stay in flight across the barrier.
__global__ __launch_bounds__(256, 3) void kfused(
    const float* __restrict__ z, const float* __restrict__ ws,
    const float* __restrict__ out_w_mv, const float* __restrict__ out_w_s,
    float* __restrict__ d_out)
{
    __shared__ float d1[128][17];                 // dg cols 0-7, sum col 8
    __shared__ float d2[128][17];                 // dq cols 0-7
    __shared__ float ssq[128];
    __shared__ float GhCh_s[16];
    __shared__ __align__(16) unsigned int Pb[8 * 512];  // bf16 s/P [h(8)][k(1024)], XOR-swizzled
    __shared__ float inv_l[8];
    __shared__ float o_sh[8 * 96];                // [h][comp]

    const int q = blockIdx.x, t = threadIdx.x;
    const int w = t >> 6, l = t & 63, lm = l & 15, lg = l >> 4;

    if (t < 16) GhCh_s[t] = ws[OFF_GH + t];

    // persistent B fragments (loaded ONCE per block)
    bf16x8 B1[4], B2[2];
    #pragma unroll
    for (int ks = 0; ks < 4; ++ks)
        B1[ks] = *(const bf16x8*)((const char*)ws + GWBT_BYTE + (lm * 128 + ks * 32 + lg * 8) * 2);
    #pragma unroll
    for (int ds = 0; ds < 2; ++ds)
        B2[ds] = *(const bf16x8*)((const char*)ws + QFB_BYTE + ((size_t)q * 1024 + lm * 64 + ds * 32 + lg * 8) * 2);

    const unsigned short* kfb = (const unsigned short*)((const char*)ws + KFB_BYTE);

    for (int kb = 0; kb < 8; ++kb) {
        // ---- prefetch z (both m-tiles) + kf fragments: stays in flight across barrier ----
        float4 za[2][4], zb[2][4];
        bf16x8 A2[2][2];
        #pragma unroll
        for (int mi = 0; mi < 2; ++mi) {
            const int krow = kb * 128 + (w * 2 + mi) * 16 + lm;
            const float* zr = z + ((size_t)q * 1024 + krow) * 128 + lg * 4;
            #pragma unroll
            for (int ks = 0; ks < 4; ++ks) {
                za[mi][ks] = *(const float4*)(zr + ks * 32);        // c = ks*32 + lg*4 + e
                zb[mi][ks] = *(const float4*)(zr + ks * 32 + 16);   // c = ks*32 + 16 + lg*4 + e
            }
            #pragma unroll
            for (int ds = 0; ds < 2; ++ds)
                A2[mi][ds] = *(const bf16x8*)(kfb + (size_t)krow * 64 + ds * 32 + lg * 8);
        }

        // ---- finalize previous iteration (LDS only; overlaps the loads above) ----
        if (kb > 0 && t < 128) {
            const int p = t >> 1, hg = t & 1;
            const int rr0 = 2 * p, rr1 = rr0 + 1;
            float mean0 = d1[rr0][8] * (1.f / 128.f);
            float var0  = ssq[rr0] * (1.f / 128.f) - mean0 * mean0;
            float rs0   = rsqrtf(var0 + 1e-5f);
            float mean1 = d1[rr1][8] * (1.f / 128.f);
            float var1  = ssq[rr1] * (1.f / 128.f) - mean1 * mean1;
            float rs1   = rsqrtf(var1 + 1e-5f);
            const int wbase = (kb - 1) * 64 + p;
            #pragma unroll
            for (int j = 0; j < 4; ++j) {
                int h = hg * 4 + j;
                float b0 = rs0 * (d1[rr0][h] - mean0 * GhCh_s[h]) + GhCh_s[8 + h];
                float s0 = d2[rr0][h] * 0.125f + b0;
                float b1 = rs1 * (d1[rr1][h] - mean1 * GhCh_s[h]) + GhCh_s[8 + h];
                float s1 = d2[rr1][h] * 0.125f + b1;
                Pb[h * 512 + (wbase ^ (h << 2))] = pk2(s0, s1);  // lo = even k
            }
        }
        LDS_BAR();   // finalize reads done before d1/d2 overwrite; z loads still in flight

        // ---- MFMA both m-tiles ----
        #pragma unroll
        for (int mi = 0; mi < 2; ++mi) {
            const int mt = w * 2 + mi;
            f32x4 acc1 = {0.f, 0.f, 0.f, 0.f};
            f32x4 acc2 = {0.f, 0.f, 0.f, 0.f};
            float sq = 0.f;
            #pragma unroll
            for (int ks = 0; ks < 4; ++ks) {
                float4 A = za[mi][ks], Bv = zb[mi][ks];
                sq = __builtin_fmaf(A.x, A.x, sq);   sq = __builtin_fmaf(A.y, A.y, sq);
                sq = __builtin_fmaf(A.z, A.z, sq);   sq = __builtin_fmaf(A.w, A.w, sq);
                sq = __builtin_fmaf(Bv.x, Bv.x, sq); sq = __builtin_fmaf(Bv.y, Bv.y, sq);
                sq = __builtin_fmaf(Bv.z, Bv.z, sq); sq = __builtin_fmaf(Bv.w, Bv.w, sq);
                u32x4 au;
                au[0] = cvtpk(A.x, A.y);   au[1] = cvtpk(A.z, A.w);
                au[2] = cvtpk(Bv.x, Bv.y); au[3] = cvtpk(Bv.z, Bv.w);
                bf16x8 af = __builtin_bit_cast(bf16x8, au);
                acc1 = __builtin_amdgcn_mfma_f32_16x16x32_bf16(af, B1[ks], acc1, 0, 0, 0);
            }
            acc2 = __builtin_amdgcn_mfma_f32_16x16x32_bf16(A2[mi][0], B2[0], acc2, 0, 0, 0);
            acc2 = __builtin_amdgcn_mfma_f32_16x16x32_bf16(A2[mi][1], B2[1], acc2, 0, 0, 0);

            sq += __shfl_xor(sq, 16);
            sq += __shfl_xor(sq, 32);
            if (lg == 0) ssq[mt * 16 + lm] = sq;

            #pragma unroll
            for (int r = 0; r < 4; ++r) {
                int row = mt * 16 + lg * 4 + r;
                d1[row][lm] = acc1[r];
                d2[row][lm] = acc2[r];
            }
        }
        LDS_BAR();   // d1/d2/ssq visible to next iteration's finalize
    }

    // ---- finalize last k-block ----
    if (t < 128) {
        const int p = t >> 1, hg = t & 1;
        const int rr0 = 2 * p, rr1 = rr0 + 1;
        float mean0 = d1[rr0][8] * (1.f / 128.f);
        float var0  = ssq[rr0] * (1.f / 128.f) - mean0 * mean0;
        float rs0   = rsqrtf(var0 + 1e-5f);
        float mean1 = d1[rr1][8] * (1.f / 128.f);
        float var1  = ssq[rr1] * (1.f / 128.f) - mean1 * mean1;
        float rs1   = rsqrtf(var1 + 1e-5f);
        const int wbase = 7 * 64 + p;
        #pragma unroll
        for (int j = 0; j < 4; ++j) {
            int h = hg * 4 + j;
            float b0 = rs0 * (d1[rr0][h] - mean0 * GhCh_s[h]) + GhCh_s[8 + h];
            float s0 = d2[rr0][h] * 0.125f + b0;
            float b1 = rs1 * (d1[rr1][h] - mean1 * GhCh_s[h]) + GhCh_s[8 + h];
            float s1 = d2[rr1][h] * 0.125f + b1;
            Pb[h * 512 + (wbase ^ (h << 2))] = pk2(s0, s1);
        }
    }
    __syncthreads();

    // ---- softmax per head, in place on bf16 Pb ----
    {
        const int h = t >> 5, e = t & 31, hx = h << 2;
        unsigned int* Ph = &Pb[h * 512];
        float m = -1e30f;
        #pragma unroll
        for (int j = 0; j < 16; ++j) {
            unsigned int v = Ph[(e + j * 32) ^ hx];
            m = fmaxf(m, fmaxf(bflo(v), bfhi(v)));
        }
        #pragma unroll
        for (int d = 16; d >= 1; d >>= 1) m = fmaxf(m, __shfl_xor(m, d));
        float lsum = 0.f;
        #pragma unroll
        for (int j = 0; j < 16; ++j) {
            int idx = (e + j * 32) ^ hx;
            unsigned int v = Ph[idx];
            float p0 = __expf(bflo(v) - m);
            float p1 = __expf(bfhi(v) - m);
            lsum += p0 + p1;
            Ph[idx] = pk2(p0, p1);
        }
        #pragma unroll
        for (int d = 16; d >= 1; d >>= 1) lsum += __shfl_xor(lsum, d);
        if (e == 0) inv_l[h] = 1.f / lsum;
    }
    __syncthreads();

    // ---- PV via MFMA: C[comp][head] = Vt(96x1024) . P^T(1024x16) ----
    {
        const unsigned short* vtb = (const unsigned short*)((const char*)ws + VTB_BYTE);
        const char* PbB = (const char*)Pb;
        const int hh = lm & 7;                     // clamp: lm 8..15 read duplicate rows (discarded)
        const int nmt = (w < 2) ? 2 : 1;
        for (int ii = 0; ii < nmt; ++ii) {
            int mt = w + ii * 4;
            f32x4 acc = {0.f, 0.f, 0.f, 0.f};
            #pragma unroll 8
            for (int ks = 0; ks < 32; ++ks) {
                bf16x8 a = *(const bf16x8*)(vtb + (size_t)(mt * 16 + lm) * 1024 + ks * 32 + lg * 8);
                bf16x8 b = *(const bf16x8*)(PbB + hh * 2048 + ((ks * 64 + lg * 16) ^ (hh << 4)));
                acc = __builtin_amdgcn_mfma_f32_16x16x32_bf16(a, b, acc, 0, 0, 0);
            }
            if (lm < 8) {
                float il = inv_l[lm];
                #pragma unroll
                for (int r = 0; r < 4; ++r)
                    o_sh[lm * 96 + mt * 16 + lg * 4 + r] = acc[r] * il;
            }
        }
    }
    __syncthreads();

    // ---- output projections ----
    {
        int o2 = t >> 4, b = t & 15, g = GRADE_C[b];
        float acc = 0.f;
        #pragma unroll
        for (int i = 0; i < 32; ++i)
            acc += o_sh[(i >> 2) * 96 + (i & 3) * 16 + b] *
                   out_w_mv[(o2 * 32 + i) * 5 + g];
        d_out[(q * 16 + o2) * 16 + b] = acc;
    }
    if (t < 128) {
        const float* wv2 = out_w_s + t * 256;
        float acc = 0.f;
        #pragma unroll 4
        for (int c = 0; c < 256; ++c)
            acc += o_sh[(c >> 5) * 96 + 64 + (c & 31)] * wv2[c];
        d_out[262144 + q * 128 + t] = acc;
    }
}

// ---------------- launch ----------------
extern "C" void kernel_launch(void* const* d_in, const int* in_sizes, int n_in,
                              void* d_out, int out_size, void* d_ws, size_t ws_size,
                              hipStream_t stream) {
    (void)in_sizes; (void)n_in; (void)out_size; (void)ws_size;
    const float* mv       = (const float*)d_in[0];
    const float* s        = (const float*)d_in[1];
    const float* z        = (const float*)d_in[2];
    const float* q_w_mv   = (const float*)d_in[3];
    const float* q_w_s    = (const float*)d_in[4];
    const float* k_w_mv   = (const float*)d_in[5];
    const float* k_w_s    = (const float*)d_in[6];
    const float* v_w_mv   = (const float*)d_in[7];
    const float* v_w_s    = (const float*)d_in[8];
    const float* out_w_mv = (const float*)d_in[9];
    const float* out_w_s  = (const float*)d_in[10];
    const float* ln_g     = (const float*)d_in[11];
    const float* ln_b     = (const float*)d_in[12];
    const float* bias_w   = (const float*)d_in[13];
    float* ws  = (float*)d_ws;
    float* out = (float*)d_out;

    kproj<<<1024, 256, 0, stream>>>(mv, s, q_w_mv, q_w_s, k_w_mv, k_w_s,
                                    v_w_mv, v_w_s, ln_g, ln_b, bias_w, ws);
    kfused<<<1024, 256, 0, stream>>>(z, ws, out_w_mv, out_w_s, out);
}